// Round 1
// baseline (778.029 us; speedup 1.0000x reference)
//
#include <hip/hip_runtime.h>

// CropAndResize: image (B=8, C=256, H=200, W=200) fp32, boxes (N,4) fp32,
// box_ind (N,) int32  ->  out (N, C, 14, 14) fp32.
// Bilinear sampling params depend only on (n,iy)/(n,ix): precompute per block
// into LDS; one block per box; coalesced flat writes over c*196+p.

#define CROP_H 14
#define CROP_W 14
#define C_DIM 256
#define H_DIM 200
#define W_DIM 200
#define PER_BOX (C_DIM * CROP_H * CROP_W)   // 50176
#define BLOCK 256

__global__ __launch_bounds__(BLOCK) void crop_and_resize_kernel(
    const float* __restrict__ image,
    const float* __restrict__ boxes,
    const int*   __restrict__ box_ind,
    float*       __restrict__ out)
{
    __shared__ int   s_ti[CROP_H], s_bi[CROP_H];
    __shared__ int   s_li[CROP_W], s_ri[CROP_W];
    __shared__ float s_ly[CROP_H], s_lx[CROP_W];
    __shared__ int   s_vy[CROP_H], s_vx[CROP_W];
    __shared__ int   s_b;

    const int n = blockIdx.x;
    const int t = threadIdx.x;

    if (t == 0) s_b = box_ind[n];
    if (t < CROP_H + CROP_W) {
        const float y1 = boxes[n * 4 + 0];
        const float x1 = boxes[n * 4 + 1];
        const float y2 = boxes[n * 4 + 2];
        const float x2 = boxes[n * 4 + 3];
        if (t < CROP_H) {
            const int iy = t;
            // height_scale = (y2 - y1) * (H-1) / (crop_h - 1)
            const float hs   = (y2 - y1) * (float)(H_DIM - 1) / (float)(CROP_H - 1);
            const float in_y = y1 * (float)(H_DIM - 1) + (float)iy * hs;
            const int   vy   = (in_y >= 0.0f) && (in_y <= (float)(H_DIM - 1));
            const float top  = floorf(in_y);
            const float ly   = in_y - top;          // from UNclipped floor (matches ref)
            int ti = (int)top;
            ti = min(max(ti, 0), H_DIM - 1);
            const int bi = min(ti + 1, H_DIM - 1);  // clip(top_i + 1) (matches ref)
            s_ti[iy] = ti; s_bi[iy] = bi; s_ly[iy] = ly; s_vy[iy] = vy;
        } else {
            const int ix = t - CROP_H;
            const float ws   = (x2 - x1) * (float)(W_DIM - 1) / (float)(CROP_W - 1);
            const float in_x = x1 * (float)(W_DIM - 1) + (float)ix * ws;
            const int   vx   = (in_x >= 0.0f) && (in_x <= (float)(W_DIM - 1));
            const float left = floorf(in_x);
            const float lx   = in_x - left;
            int li = (int)left;
            li = min(max(li, 0), W_DIM - 1);
            const int ri = min(li + 1, W_DIM - 1);
            s_li[ix] = li; s_ri[ix] = ri; s_lx[ix] = lx; s_vx[ix] = vx;
        }
    }
    __syncthreads();

    const int b = s_b;
    const float* __restrict__ imgb = image + (size_t)b * C_DIM * H_DIM * W_DIM;
    float* __restrict__ outb = out + (size_t)n * PER_BOX;

    for (int j = t; j < PER_BOX; j += BLOCK) {
        const int c  = j / (CROP_H * CROP_W);
        const int p  = j - c * (CROP_H * CROP_W);
        const int iy = p / CROP_W;
        const int ix = p - iy * CROP_W;

        float v = 0.0f;  // EXTRAPOLATION_VALUE
        if (s_vy[iy] & s_vx[ix]) {
            const float* __restrict__ base = imgb + (size_t)c * (H_DIM * W_DIM);
            const int ti = s_ti[iy], bi = s_bi[iy];
            const int li = s_li[ix], ri = s_ri[ix];
            const float tl = base[ti * W_DIM + li];
            const float tr = base[ti * W_DIM + ri];
            const float bl = base[bi * W_DIM + li];
            const float br = base[bi * W_DIM + ri];
            const float lx = s_lx[ix];
            const float ly = s_ly[iy];
            const float top_v = tl + (tr - tl) * lx;
            const float bot_v = bl + (br - bl) * lx;
            v = top_v + (bot_v - top_v) * ly;
        }
        outb[j] = v;
    }
}

extern "C" void kernel_launch(void* const* d_in, const int* in_sizes, int n_in,
                              void* d_out, int out_size, void* d_ws, size_t ws_size,
                              hipStream_t stream) {
    const float* image   = (const float*)d_in[0];
    const float* boxes   = (const float*)d_in[1];
    const int*   box_ind = (const int*)d_in[2];
    float*       out     = (float*)d_out;

    const int N = in_sizes[2];  // number of boxes (1000)

    crop_and_resize_kernel<<<dim3(N), dim3(BLOCK), 0, stream>>>(image, boxes, box_ind, out);
}

// Round 2
// 704.638 us; speedup vs baseline: 1.1042x; 1.1042x over previous
//
#include <hip/hip_runtime.h>

// CropAndResize: image (8,256,200,200) fp32, boxes (N,4), box_ind (N,) ->
// out (N,256,14,14) fp32.
// R2: (1) counting-sort boxes by image index so concurrently-running blocks
// share one ~41MB image (L2/L3 locality, cuts HBM re-fetch); (2) 4 channel-
// chunks per box -> 4000 blocks, lifts grid-capped occupancy; (3) predicated
// (branch-free) gather so loads from unrolled iterations stay in flight.

#define CROP_H 14
#define CROP_W 14
#define C_DIM 256
#define H_DIM 200
#define W_DIM 200
#define HW (H_DIM * W_DIM)
#define PER_BOX (C_DIM * CROP_H * CROP_W)   // 50176
#define BLOCK 256
#define CHUNKS 4
#define C_PER (C_DIM / CHUNKS)              // 64 channels per block
#define ELEMS (C_PER * CROP_H * CROP_W)     // 12544 elements per block

__global__ __launch_bounds__(BLOCK) void sort_boxes_kernel(
    const int* __restrict__ box_ind, int N, int* __restrict__ perm)
{
    __shared__ int cnt[8];
    __shared__ int base[8];
    const int t = threadIdx.x;
    if (t < 8) cnt[t] = 0;
    __syncthreads();
    for (int i = t; i < N; i += BLOCK) atomicAdd(&cnt[box_ind[i]], 1);
    __syncthreads();
    if (t == 0) {
        int run = 0;
        for (int b = 0; b < 8; ++b) { base[b] = run; run += cnt[b]; }
    }
    __syncthreads();
    for (int i = t; i < N; i += BLOCK) {
        const int pos = atomicAdd(&base[box_ind[i]], 1);
        perm[pos] = i;
    }
}

__global__ __launch_bounds__(BLOCK) void crop_and_resize_kernel(
    const float* __restrict__ image,
    const float* __restrict__ boxes,
    const int*   __restrict__ box_ind,
    const int*   __restrict__ perm,
    float*       __restrict__ out)
{
    __shared__ int   s_ti[CROP_H], s_bi[CROP_H];
    __shared__ int   s_li[CROP_W], s_ri[CROP_W];
    __shared__ float s_ly[CROP_H], s_lx[CROP_W];
    __shared__ int   s_vy[CROP_H], s_vx[CROP_W];
    __shared__ int   s_b;

    const int slot  = blockIdx.x / CHUNKS;
    const int chunk = blockIdx.x % CHUNKS;
    const int t     = threadIdx.x;

    __shared__ int s_n;
    if (t == 0) s_n = perm[slot];
    __syncthreads();
    const int n = s_n;

    if (t == 0) s_b = box_ind[n];
    if (t < CROP_H + CROP_W) {
        const float y1 = boxes[n * 4 + 0];
        const float x1 = boxes[n * 4 + 1];
        const float y2 = boxes[n * 4 + 2];
        const float x2 = boxes[n * 4 + 3];
        if (t < CROP_H) {
            const int iy = t;
            const float hs   = (y2 - y1) * (float)(H_DIM - 1) / (float)(CROP_H - 1);
            const float in_y = y1 * (float)(H_DIM - 1) + (float)iy * hs;
            const int   vy   = (in_y >= 0.0f) && (in_y <= (float)(H_DIM - 1));
            const float top  = floorf(in_y);
            const float ly   = in_y - top;          // from UNclipped floor (matches ref)
            int ti = (int)top;
            ti = min(max(ti, 0), H_DIM - 1);
            const int bi = min(ti + 1, H_DIM - 1);
            s_ti[iy] = ti; s_bi[iy] = bi; s_ly[iy] = ly; s_vy[iy] = vy;
        } else {
            const int ix = t - CROP_H;
            const float ws   = (x2 - x1) * (float)(W_DIM - 1) / (float)(CROP_W - 1);
            const float in_x = x1 * (float)(W_DIM - 1) + (float)ix * ws;
            const int   vx   = (in_x >= 0.0f) && (in_x <= (float)(W_DIM - 1));
            const float left = floorf(in_x);
            const float lx   = in_x - left;
            int li = (int)left;
            li = min(max(li, 0), W_DIM - 1);
            const int ri = min(li + 1, W_DIM - 1);
            s_li[ix] = li; s_ri[ix] = ri; s_lx[ix] = lx; s_vx[ix] = vx;
        }
    }
    __syncthreads();

    const float* __restrict__ imgb = image + (size_t)s_b * (C_DIM * HW)
                                           + (size_t)chunk * (C_PER * HW);
    float* __restrict__ outb = out + (size_t)n * PER_BOX + (size_t)chunk * ELEMS;

    #pragma unroll 4
    for (int j = t; j < ELEMS; j += BLOCK) {
        const int c  = j / (CROP_H * CROP_W);
        const int p  = j - c * (CROP_H * CROP_W);
        const int iy = p / CROP_W;
        const int ix = p - iy * CROP_W;

        const int ti = s_ti[iy], bi = s_bi[iy];
        const int li = s_li[ix], ri = s_ri[ix];
        const float* __restrict__ base = imgb + (size_t)c * HW;

        // unconditional loads (indices pre-clamped -> always in bounds)
        const float tl = base[ti * W_DIM + li];
        const float tr = base[ti * W_DIM + ri];
        const float bl = base[bi * W_DIM + li];
        const float br = base[bi * W_DIM + ri];

        const float lx = s_lx[ix];
        const float ly = s_ly[iy];
        const float top_v = tl + (tr - tl) * lx;
        const float bot_v = bl + (br - bl) * lx;
        float v = top_v + (bot_v - top_v) * ly;

        v = (s_vy[iy] & s_vx[ix]) ? v : 0.0f;   // predicated extrapolation
        outb[j] = v;
    }
}

extern "C" void kernel_launch(void* const* d_in, const int* in_sizes, int n_in,
                              void* d_out, int out_size, void* d_ws, size_t ws_size,
                              hipStream_t stream) {
    const float* image   = (const float*)d_in[0];
    const float* boxes   = (const float*)d_in[1];
    const int*   box_ind = (const int*)d_in[2];
    float*       out     = (float*)d_out;
    int*         perm    = (int*)d_ws;          // N ints of scratch

    const int N = in_sizes[2];  // number of boxes (1000)

    sort_boxes_kernel<<<dim3(1), dim3(BLOCK), 0, stream>>>(box_ind, N, perm);
    crop_and_resize_kernel<<<dim3(N * CHUNKS), dim3(BLOCK), 0, stream>>>(
        image, boxes, box_ind, perm, out);
}